// Round 1
// baseline (135.347 us; speedup 1.0000x reference)
//
#include <hip/hip_runtime.h>
#include <math.h>

// Problem constants (fixed by reference setup_inputs / module constants)
#define BB   8      // batch
#define NP   4096   // proposals per image
#define NG   512    // gt boxes per image
#define TT   200    // TRAIN_ROIS
#define PMAX 66     // int(200 * 0.33)

// ---------------------------------------------------------------------------
// Phase A: per proposal, max IoU over gt boxes (invalid gt -> -1) and
// first-argmax (matches jnp.argmax tie-break via strict >).
// Grid: BB*16 blocks (16 chunks of 256 proposals per image), 256 threads.
// ---------------------------------------------------------------------------
__global__ __launch_bounds__(256) void iou_phase(
    const float* __restrict__ proposals, const float* __restrict__ gt,
    float* __restrict__ maxiou, int* __restrict__ argj) {
#pragma clang fp contract(off)
  const int b     = blockIdx.x >> 4;
  const int chunk = blockIdx.x & 15;

  __shared__ float sgx[NG], sgy[NG], sgz[NG], sgw[NG];
  __shared__ float sval[NG];

  const float* gtb = gt + (size_t)b * NG * 4;
  for (int j = threadIdx.x; j < NG; j += 256) {
    float g0 = gtb[j * 4 + 0], g1 = gtb[j * 4 + 1];
    float g2 = gtb[j * 4 + 2], g3 = gtb[j * 4 + 3];
    sgx[j] = g0; sgy[j] = g1; sgz[j] = g2; sgw[j] = g3;
    sval[j] = (fabsf(g0) + fabsf(g1) + fabsf(g2) + fabsf(g3)) > 0.0f ? 1.0f : 0.0f;
  }
  __syncthreads();

  const int i = chunk * 256 + threadIdx.x;
  const float* pp = proposals + ((size_t)b * NP + i) * 4;
  const float p0 = pp[0], p1 = pp[1], p2 = pp[2], p3 = pp[3];
  const float a1 = (p2 - p0) * (p3 - p1);

  float best = -INFINITY;
  int bj = 0;
  for (int j = 0; j < NG; ++j) {
    float g0 = sgx[j], g1 = sgy[j], g2 = sgz[j], g3 = sgw[j];
    // exact reference op order (fp contract off => IEEE, matches numpy/JAX f32)
    float y1 = fmaxf(p0, g0);
    float x1 = fmaxf(p1, g1);
    float y2 = fminf(p2, g2);
    float x2 = fminf(p3, g3);
    float inter = fmaxf(x2 - x1, 0.0f) * fmaxf(y2 - y1, 0.0f);
    float a2 = (g2 - g0) * (g3 - g1);
    float un = a1 + a2 - inter;
    float iou = inter / (un > 0.0f ? un : 1.0f);
    float v = (sval[j] > 0.0f) ? iou : -1.0f;   // invalid gt column -> -1
    if (v > best) { best = v; bj = j; }          // strict > = first-max argmax
  }
  maxiou[(size_t)b * NP + i] = best;
  argj[(size_t)b * NP + i]   = bj;
}

// ---------------------------------------------------------------------------
// Phase B: per image (1 block), ordered compaction of pos/neg indices with a
// single wave (ballot + prefix popcount), then each thread owns one output
// slot exclusively (pos values / neg rois / zeros) -> every output element
// written exactly once (required: d_out is re-poisoned to 0xAA each launch).
// ---------------------------------------------------------------------------
__global__ __launch_bounds__(256) void select_phase(
    const float* __restrict__ proposals, const float* __restrict__ gt,
    const int* __restrict__ caps, const float* __restrict__ scores,
    const float* __restrict__ maxiou, const int* __restrict__ argj,
    float* __restrict__ out) {
#pragma clang fp contract(off)
  const int b = blockIdx.x;

  __shared__ int s_pos[PMAX];
  __shared__ int s_neg[TT];
  __shared__ int s_cnt[2];

  // Output slices (flat concat in return order: rois, deltas, caps, scores)
  float* rois   = out + (size_t)b * TT * 4;
  float* deltas = out + (size_t)BB * TT * 4 + (size_t)b * TT * 4;
  float* ocaps  = out + (size_t)2 * BB * TT * 4 + (size_t)b * TT * 15;
  float* osc    = out + (size_t)2 * BB * TT * 4 + (size_t)BB * TT * 15 + (size_t)b * TT;

  if (threadIdx.x < 64) {
    const int lane = threadIdx.x;
    int pos_total = 0, neg_total = 0;
    const float* pb  = proposals + (size_t)b * NP * 4;
    const float* mib = maxiou + (size_t)b * NP;
    for (int base = 0; base < NP; base += 64) {
      int i = base + lane;
      float q0 = pb[i * 4 + 0], q1 = pb[i * 4 + 1];
      float q2 = pb[i * 4 + 2], q3 = pb[i * 4 + 3];
      bool vp = (fabsf(q0) + fabsf(q1) + fabsf(q2) + fabsf(q3)) > 0.0f;
      float mi = mib[i];
      bool isp = vp && (mi >= 0.5f);
      bool isn = vp && (mi < 0.5f);
      unsigned long long mp = __ballot(isp);
      unsigned long long mn = __ballot(isn);
      unsigned long long lower = (1ull << lane) - 1ull;
      if (isp) {
        int k = pos_total + __popcll(mp & lower);
        if (k < PMAX) s_pos[k] = i;
      }
      if (isn) {
        int k = neg_total + __popcll(mn & lower);
        if (k < TT) s_neg[k] = i;
      }
      pos_total += __popcll(mp);
      neg_total += __popcll(mn);
    }
    if (lane == 0) {
      int pos_cnt = pos_total < PMAX ? pos_total : PMAX;
      // f32 semantics (JAX x64-off): 0.33f > 0.33, e.g. 66/0.33f -> 199 (trunc)
      int neg_target = (int)((float)pos_cnt / 0.33f) - pos_cnt;
      int neg_cnt = neg_target;
      if (neg_total < neg_cnt)     neg_cnt = neg_total;
      if (TT - pos_cnt < neg_cnt)  neg_cnt = TT - pos_cnt;
      if (neg_cnt < 0)             neg_cnt = 0;
      s_cnt[0] = pos_cnt;
      s_cnt[1] = neg_cnt;
    }
  }
  __syncthreads();

  const int pos_cnt = s_cnt[0];
  const int neg_cnt = s_cnt[1];
  const int k = threadIdx.x;

  if (k < TT) {
    if (k < pos_cnt) {
      // positive slot: roi, deltas, captions, score
      int i = s_pos[k];
      const float* pp = proposals + ((size_t)b * NP + i) * 4;
      float p0 = pp[0], p1 = pp[1], p2 = pp[2], p3 = pp[3];
      int g = argj[(size_t)b * NP + i];
      const float* gg = gt + ((size_t)b * NG + g) * 4;
      float g0 = gg[0], g1 = gg[1], g2 = gg[2], g3 = gg[3];

      rois[k * 4 + 0] = p0; rois[k * 4 + 1] = p1;
      rois[k * 4 + 2] = p2; rois[k * 4 + 3] = p3;

      float h  = p2 - p0, w  = p3 - p1;
      float cy = p0 + 0.5f * h, cx = p1 + 0.5f * w;
      float gh = g2 - g0, gw = g3 - g1;
      float gcy = g0 + 0.5f * gh, gcx = g1 + 0.5f * gw;
      deltas[k * 4 + 0] = ((gcy - cy) / h) / 0.1f;
      deltas[k * 4 + 1] = ((gcx - cx) / w) / 0.1f;
      deltas[k * 4 + 2] = logf(gh / h) / 0.2f;
      deltas[k * 4 + 3] = logf(gw / w) / 0.2f;

      const int* cp = caps + ((size_t)b * NG + g) * 15;
      for (int c = 0; c < 15; ++c) ocaps[k * 15 + c] = (float)cp[c];
      osc[k] = scores[(size_t)b * NG + g];
    } else {
      // negative or empty slot: roi from neg list or zero; rest zero
      if (k < pos_cnt + neg_cnt) {
        int i = s_neg[k - pos_cnt];
        const float* pp = proposals + ((size_t)b * NP + i) * 4;
        rois[k * 4 + 0] = pp[0]; rois[k * 4 + 1] = pp[1];
        rois[k * 4 + 2] = pp[2]; rois[k * 4 + 3] = pp[3];
      } else {
        rois[k * 4 + 0] = 0.0f; rois[k * 4 + 1] = 0.0f;
        rois[k * 4 + 2] = 0.0f; rois[k * 4 + 3] = 0.0f;
      }
      deltas[k * 4 + 0] = 0.0f; deltas[k * 4 + 1] = 0.0f;
      deltas[k * 4 + 2] = 0.0f; deltas[k * 4 + 3] = 0.0f;
      for (int c = 0; c < 15; ++c) ocaps[k * 15 + c] = 0.0f;
      osc[k] = 0.0f;
    }
  }
}

extern "C" void kernel_launch(void* const* d_in, const int* in_sizes, int n_in,
                              void* d_out, int out_size, void* d_ws, size_t ws_size,
                              hipStream_t stream) {
  const float* proposals = (const float*)d_in[0];  // (8,4096,4) f32
  const float* gt        = (const float*)d_in[1];  // (8,512,4)  f32
  const int*   caps      = (const int*)d_in[2];    // (8,512,15) i32
  const float* scores    = (const float*)d_in[3];  // (8,512)    f32
  float* out = (float*)d_out;                      // 38400 f32 (flat tuple)

  float* maxiou = (float*)d_ws;                                   // 8*4096 f32
  int*   argj   = (int*)((char*)d_ws + (size_t)BB * NP * sizeof(float)); // 8*4096 i32

  hipLaunchKernelGGL(iou_phase, dim3(BB * 16), dim3(256), 0, stream,
                     proposals, gt, maxiou, argj);
  hipLaunchKernelGGL(select_phase, dim3(BB), dim3(256), 0, stream,
                     proposals, gt, caps, scores, maxiou, argj, out);
}

// Round 2
// 82.967 us; speedup vs baseline: 1.6313x; 1.6313x over previous
//
#include <hip/hip_runtime.h>
#include <math.h>

// Problem constants (fixed by reference setup_inputs / module constants)
#define BB   8      // batch
#define NP   4096   // proposals per image
#define NG   512    // gt boxes per image
#define TT   200    // TRAIN_ROIS
#define PMAX 66     // int(200 * 0.33)

#define CH   8      // gt chunks per block
#define CSZ  64     // gts per chunk (CH*CSZ == NG)
#define PB   32     // proposals per block (256 threads / CH)

// ---------------------------------------------------------------------------
// Phase A: per proposal, max IoU over gt boxes (invalid gt -> -1) and
// first-argmax (jnp.argmax tie-break). Parallelized over gt chunks:
// 256 threads = 32 proposals x 8 chunks of 64 gts; LDS reduce in chunk
// order with strict > preserves first-max semantics exactly.
// Grid: BB * (NP/PB) = 1024 blocks -> ~16 waves/CU (vs 2 before).
// Also classifies each proposal: cls = 0 invalid, 1 negative, 2 positive.
// ---------------------------------------------------------------------------
__global__ __launch_bounds__(256) void iou_phase(
    const float* __restrict__ proposals, const float* __restrict__ gt,
    int* __restrict__ argj, int* __restrict__ cls) {
#pragma clang fp contract(off)
  const int b     = blockIdx.x >> 7;          // / 128
  const int pbase = (blockIdx.x & 127) * PB;

  __shared__ float4 sgt[NG];
  __shared__ float  sa2[NG];
  __shared__ float  sv[NG];
  __shared__ float  rbest[CH][PB];
  __shared__ int    ridx[CH][PB];

  const int tid = threadIdx.x;

  // Stage gt boxes (+ precomputed area a2, valid flag) — 2 per thread.
  const float4* gtb4 = (const float4*)(gt + (size_t)b * NG * 4);
  for (int j = tid; j < NG; j += 256) {
    float4 g = gtb4[j];
    sgt[j] = g;
    sa2[j] = (g.z - g.x) * (g.w - g.y);   // same expr/order as reference a2
    sv[j]  = (fabsf(g.x) + fabsf(g.y) + fabsf(g.z) + fabsf(g.w)) > 0.0f ? 1.0f : 0.0f;
  }
  __syncthreads();

  const int plocal  = tid & (PB - 1);
  const int chunkid = tid >> 5;              // tid / PB
  const int i       = pbase + plocal;
  const int jbase   = chunkid * CSZ;

  const float4 p = ((const float4*)(proposals))[(size_t)b * NP + i];
  const float p0 = p.x, p1 = p.y, p2 = p.z, p3 = p.w;
  const float a1 = (p2 - p0) * (p3 - p1);

  float best = -INFINITY;
  int bj = jbase;
  for (int jj = 0; jj < CSZ; ++jj) {
    int j = jbase + jj;
    float4 g = sgt[j];                        // 32-lane broadcast (conflict-free)
    // exact reference op order (fp contract off => IEEE, matches numpy/JAX f32)
    float y1 = fmaxf(p0, g.x);
    float x1 = fmaxf(p1, g.y);
    float y2 = fminf(p2, g.z);
    float x2 = fminf(p3, g.w);
    float inter = fmaxf(x2 - x1, 0.0f) * fmaxf(y2 - y1, 0.0f);
    float un = a1 + sa2[j] - inter;           // (a1 + a2) - inter
    float iou = inter / (un > 0.0f ? un : 1.0f);
    float v = (sv[j] != 0.0f) ? iou : -1.0f;  // invalid gt column -> -1
    if (v > best) { best = v; bj = j; }       // strict > = first-max argmax
  }
  rbest[chunkid][plocal] = best;
  ridx[chunkid][plocal]  = bj;
  __syncthreads();

  // Threads 0..31 (chunk 0) combine the 8 chunk partials in chunk order.
  if (tid < PB) {
    float bb = rbest[0][tid];
    int   bi = ridx[0][tid];
    for (int c = 1; c < CH; ++c) {
      float v = rbest[c][tid];
      if (v > bb) { bb = v; bi = ridx[c][tid]; }  // tie -> earlier chunk (smaller j)
    }
    // This thread is chunk 0 / proposal tid: p0..p3 registers hold its proposal.
    bool vp = (fabsf(p0) + fabsf(p1) + fabsf(p2) + fabsf(p3)) > 0.0f;
    int c = vp ? (bb >= 0.5f ? 2 : 1) : 0;
    argj[(size_t)b * NP + i] = bi;
    cls[(size_t)b * NP + i]  = c;
  }
}

// ---------------------------------------------------------------------------
// Phase B: per image (1 block, 4 waves). Each wave scans a quarter of the
// proposals via ballot+prefix-popcount into wave-local ordered pos/neg lists
// (local slot index <= global slot index, so PMAX/TT caps are lossless).
// Slot threads then resolve their source via prefix counts and write every
// output element exactly once (d_out is re-poisoned each launch).
// ---------------------------------------------------------------------------
__global__ __launch_bounds__(256) void select_phase(
    const float* __restrict__ proposals, const float* __restrict__ gt,
    const int* __restrict__ caps, const float* __restrict__ scores,
    const int* __restrict__ argj, const int* __restrict__ cls,
    float* __restrict__ out) {
#pragma clang fp contract(off)
  const int b = blockIdx.x;

  __shared__ int s_posL[4][PMAX];
  __shared__ int s_negL[4][TT];
  __shared__ int s_pc[4], s_nc[4];

  const int tid  = threadIdx.x;
  const int w    = tid >> 6;
  const int lane = tid & 63;

  const int* clsb = cls + (size_t)b * NP;
  {
    int pcnt = 0, ncnt = 0;
    const int ibase = w * (NP / 4);
    for (int it = 0; it < NP / 4 / 64; ++it) {
      int i = ibase + it * 64 + lane;
      int c = clsb[i];
      unsigned long long mp = __ballot(c == 2);
      unsigned long long mn = __ballot(c == 1);
      unsigned long long lower = (1ull << lane) - 1ull;
      if (c == 2) {
        int k = pcnt + __popcll(mp & lower);
        if (k < PMAX) s_posL[w][k] = i;
      }
      if (c == 1) {
        int k = ncnt + __popcll(mn & lower);
        if (k < TT) s_negL[w][k] = i;
      }
      pcnt += __popcll(mp);
      ncnt += __popcll(mn);
    }
    if (lane == 0) { s_pc[w] = pcnt; s_nc[w] = ncnt; }
  }
  __syncthreads();

  const int pos_total = s_pc[0] + s_pc[1] + s_pc[2] + s_pc[3];
  const int neg_total = s_nc[0] + s_nc[1] + s_nc[2] + s_nc[3];
  int pos_cnt = pos_total < PMAX ? pos_total : PMAX;
  // f32 semantics (JAX x64-off): 0.33f > 0.33, e.g. 66/0.33f -> 199 (trunc)
  int neg_cnt = (int)((float)pos_cnt / 0.33f) - pos_cnt;
  if (neg_total < neg_cnt)    neg_cnt = neg_total;
  if (TT - pos_cnt < neg_cnt) neg_cnt = TT - pos_cnt;
  if (neg_cnt < 0)            neg_cnt = 0;

  // Output slices (flat concat in return order: rois, deltas, caps, scores)
  float* rois   = out + (size_t)b * TT * 4;
  float* deltas = out + (size_t)BB * TT * 4 + (size_t)b * TT * 4;
  float* ocaps  = out + (size_t)2 * BB * TT * 4 + (size_t)b * TT * 15;
  float* osc    = out + (size_t)2 * BB * TT * 4 + (size_t)BB * TT * 15 + (size_t)b * TT;

  const int k = tid;
  if (k < TT) {
    if (k < pos_cnt) {
      int rem = k, w2 = 0;
      while (rem >= s_pc[w2]) { rem -= s_pc[w2]; ++w2; }
      int i = s_posL[w2][rem];

      const float* pp = proposals + ((size_t)b * NP + i) * 4;
      float p0 = pp[0], p1 = pp[1], p2 = pp[2], p3 = pp[3];
      int g = argj[(size_t)b * NP + i];
      const float* gg = gt + ((size_t)b * NG + g) * 4;
      float g0 = gg[0], g1 = gg[1], g2 = gg[2], g3 = gg[3];

      rois[k * 4 + 0] = p0; rois[k * 4 + 1] = p1;
      rois[k * 4 + 2] = p2; rois[k * 4 + 3] = p3;

      float h  = p2 - p0, ww = p3 - p1;
      float cy = p0 + 0.5f * h, cx = p1 + 0.5f * ww;
      float gh = g2 - g0, gw = g3 - g1;
      float gcy = g0 + 0.5f * gh, gcx = g1 + 0.5f * gw;
      deltas[k * 4 + 0] = ((gcy - cy) / h) / 0.1f;
      deltas[k * 4 + 1] = ((gcx - cx) / ww) / 0.1f;
      deltas[k * 4 + 2] = logf(gh / h) / 0.2f;
      deltas[k * 4 + 3] = logf(gw / ww) / 0.2f;

      const int* cp = caps + ((size_t)b * NG + g) * 15;
      for (int c = 0; c < 15; ++c) ocaps[k * 15 + c] = (float)cp[c];
      osc[k] = scores[(size_t)b * NG + g];
    } else {
      if (k < pos_cnt + neg_cnt) {
        int m = k - pos_cnt, w2 = 0;
        while (m >= s_nc[w2]) { m -= s_nc[w2]; ++w2; }
        int i = s_negL[w2][m];
        const float* pp = proposals + ((size_t)b * NP + i) * 4;
        rois[k * 4 + 0] = pp[0]; rois[k * 4 + 1] = pp[1];
        rois[k * 4 + 2] = pp[2]; rois[k * 4 + 3] = pp[3];
      } else {
        rois[k * 4 + 0] = 0.0f; rois[k * 4 + 1] = 0.0f;
        rois[k * 4 + 2] = 0.0f; rois[k * 4 + 3] = 0.0f;
      }
      deltas[k * 4 + 0] = 0.0f; deltas[k * 4 + 1] = 0.0f;
      deltas[k * 4 + 2] = 0.0f; deltas[k * 4 + 3] = 0.0f;
      for (int c = 0; c < 15; ++c) ocaps[k * 15 + c] = 0.0f;
      osc[k] = 0.0f;
    }
  }
}

extern "C" void kernel_launch(void* const* d_in, const int* in_sizes, int n_in,
                              void* d_out, int out_size, void* d_ws, size_t ws_size,
                              hipStream_t stream) {
  const float* proposals = (const float*)d_in[0];  // (8,4096,4) f32
  const float* gt        = (const float*)d_in[1];  // (8,512,4)  f32
  const int*   caps      = (const int*)d_in[2];    // (8,512,15) i32
  const float* scores    = (const float*)d_in[3];  // (8,512)    f32
  float* out = (float*)d_out;                      // 38400 f32 (flat tuple)

  int* argj = (int*)d_ws;                                        // 8*4096 i32
  int* cls  = (int*)((char*)d_ws + (size_t)BB * NP * sizeof(int)); // 8*4096 i32

  hipLaunchKernelGGL(iou_phase, dim3(BB * (NP / PB)), dim3(256), 0, stream,
                     proposals, gt, argj, cls);
  hipLaunchKernelGGL(select_phase, dim3(BB), dim3(256), 0, stream,
                     proposals, gt, caps, scores, argj, cls, out);
}

// Round 3
// 81.481 us; speedup vs baseline: 1.6611x; 1.0182x over previous
//
#include <hip/hip_runtime.h>
#include <math.h>

// Problem constants (fixed by reference setup_inputs / module constants)
#define BB   8      // batch
#define NP   4096   // proposals per image
#define NG   512    // gt boxes per image
#define TT   200    // TRAIN_ROIS
#define PMAX 66     // int(200 * 0.33)

#define CH   8      // gt chunks per block
#define PB   32     // proposals per block (256 threads / CH)
#define NBLK (NP / PB)   // 128 proposal-blocks per image

// ---------------------------------------------------------------------------
// Phase A: per proposal, max IoU over gt boxes and first-argmax (jnp.argmax
// tie-break). Wave 0 compacts VALID gts into LDS (stable -> ascending j), so
// the main loop skips invalid columns: they can never win (iou >= 0 > -1).
// 256 threads = 32 proposals x 8 ordered chunks; chunk-order strict-> reduce
// preserves first-max semantics exactly. Emits per-block 32-bit pos/neg
// ballot masks (bit l = proposal pbase+l) + argj for every proposal.
// Grid: BB * 128 = 1024 blocks.
// ---------------------------------------------------------------------------
__global__ __launch_bounds__(256) void iou_phase(
    const float* __restrict__ proposals, const float* __restrict__ gt,
    int* __restrict__ argj, unsigned int* __restrict__ posmask,
    unsigned int* __restrict__ negmask) {
#pragma clang fp contract(off)
  const int b     = blockIdx.x >> 7;          // / 128
  const int blk   = blockIdx.x & 127;
  const int pbase = blk * PB;

  __shared__ float4 sgt[NG];    // compacted valid gt boxes (ascending j)
  __shared__ float  sa2[NG];    // their areas (reference expr/order)
  __shared__ short  sidx[NG];   // their original j
  __shared__ int    s_nv;
  __shared__ float  rbest[CH][PB];
  __shared__ int    ridx[CH][PB];

  const int tid = threadIdx.x;

  // Wave 0: stable compaction of valid gts (ballot + prefix popcount).
  if (tid < 64) {
    const float4* gtb4 = (const float4*)(gt + (size_t)b * NG * 4);
    int cnt = 0;
    for (int base = 0; base < NG; base += 64) {
      int j = base + tid;
      float4 g = gtb4[j];
      bool v = (fabsf(g.x) + fabsf(g.y) + fabsf(g.z) + fabsf(g.w)) > 0.0f;
      unsigned long long m = __ballot(v);
      if (v) {
        int k = cnt + __popcll(m & ((1ull << tid) - 1ull));
        sgt[k]  = g;
        sa2[k]  = (g.z - g.x) * (g.w - g.y);  // same expr/order as reference a2
        sidx[k] = (short)j;
      }
      cnt += __popcll(m);
    }
    if (tid == 0) s_nv = cnt;
  }
  __syncthreads();

  const int nv  = s_nv;
  const int csz = (nv + CH - 1) / CH;

  const int plocal  = tid & (PB - 1);
  const int chunkid = tid >> 5;              // tid / PB
  const int i       = pbase + plocal;

  const float4 p = ((const float4*)proposals)[(size_t)b * NP + i];
  const float a1 = (p.z - p.x) * (p.w - p.y);

  int j0 = chunkid * csz;
  int j1 = j0 + csz; if (j1 > nv) j1 = nv;
  if (j0 > nv) j0 = nv;

  float best = -INFINITY;
  int bj = 0;
  for (int j = j0; j < j1; ++j) {
    float4 g = sgt[j];                        // 32-lane broadcast (conflict-free)
    // exact reference op order (fp contract off => IEEE, matches numpy/JAX f32)
    float y1 = fmaxf(p.x, g.x);
    float x1 = fmaxf(p.y, g.y);
    float y2 = fminf(p.z, g.z);
    float x2 = fminf(p.w, g.w);
    float inter = fmaxf(x2 - x1, 0.0f) * fmaxf(y2 - y1, 0.0f);
    float un = a1 + sa2[j] - inter;           // (a1 + a2) - inter
    float iou = inter / (un > 0.0f ? un : 1.0f);
    if (iou > best) { best = iou; bj = (int)sidx[j]; }  // strict > = first-max
  }
  rbest[chunkid][plocal] = best;
  ridx[chunkid][plocal]  = bj;
  __syncthreads();

  // Threads 0..31 (lanes 0..31 of wave 0) combine the 8 chunk partials in
  // chunk order (chunks cover ascending original j -> first-max preserved).
  if (tid < PB) {
    float bb = rbest[0][tid];
    int   bi = ridx[0][tid];
    for (int c = 1; c < CH; ++c) {
      float v = rbest[c][tid];
      if (v > bb) { bb = v; bi = ridx[c][tid]; }
    }
    bool vp  = (fabsf(p.x) + fabsf(p.y) + fabsf(p.z) + fabsf(p.w)) > 0.0f;
    bool isp = vp && (bb >= 0.5f);
    bool isn = vp && (bb <  0.5f);
    unsigned long long mp = __ballot(isp);   // lanes 32..63 inactive -> 0 bits
    unsigned long long mn = __ballot(isn);
    argj[(size_t)b * NP + i] = bi;
    if (tid == 0) {
      posmask[(size_t)b * NBLK + blk] = (unsigned int)mp;
      negmask[(size_t)b * NBLK + blk] = (unsigned int)mn;
    }
  }
}

// ---------------------------------------------------------------------------
// Phase B: per image (1 block). Load 128 pos + 128 neg masks, Hillis-Steele
// popcount prefix scan (both halves in parallel), bit-emit ordered index
// lists (caps PMAX/TT), then each thread owns one output slot exclusively
// and writes every output element exactly once (d_out re-poisoned per launch).
// ---------------------------------------------------------------------------
__global__ __launch_bounds__(256) void select_phase(
    const float* __restrict__ proposals, const float* __restrict__ gt,
    const int* __restrict__ caps, const float* __restrict__ scores,
    const int* __restrict__ argj, const unsigned int* __restrict__ posmask,
    const unsigned int* __restrict__ negmask, float* __restrict__ out) {
#pragma clang fp contract(off)
  const int b = blockIdx.x;

  __shared__ unsigned int s_pm[NBLK], s_nm[NBLK];
  __shared__ int sc[256];                 // [0:128) pos scan, [128:256) neg scan
  __shared__ int s_pos[PMAX];
  __shared__ int s_neg[TT];

  const int tid = threadIdx.x;
  const int t   = tid & 127;

  if (tid < NBLK) {
    s_pm[tid] = posmask[(size_t)b * NBLK + tid];
    s_nm[tid] = negmask[(size_t)b * NBLK + tid];
  }
  __syncthreads();

  sc[tid] = (tid < 128) ? __popc(s_pm[t]) : __popc(s_nm[t]);
  __syncthreads();
  // inclusive scan within each 128-half (tid-off stays in-half since t>=off)
  for (int off = 1; off < 128; off <<= 1) {
    int v   = sc[tid];
    int add = (t >= off) ? sc[tid - off] : 0;
    __syncthreads();
    sc[tid] = v + add;
    __syncthreads();
  }

  const int pos_total = sc[127];
  const int neg_total = sc[255];

  // Emit ordered index lists (ascending proposal index; stable by construction).
  if (tid < 128) {
    unsigned int pm = s_pm[tid];
    int base = (t == 0) ? 0 : sc[tid - 1];
    while (pm && base < PMAX) {
      int bit = __ffs(pm) - 1;
      s_pos[base] = tid * PB + bit;
      pm &= pm - 1;
      ++base;
    }
  } else {
    unsigned int nm = s_nm[t];
    int base = (t == 0) ? 0 : sc[tid - 1];
    while (nm && base < TT) {
      int bit = __ffs(nm) - 1;
      s_neg[base] = t * PB + bit;
      nm &= nm - 1;
      ++base;
    }
  }
  __syncthreads();

  int pos_cnt = pos_total < PMAX ? pos_total : PMAX;
  // f32 semantics (JAX x64-off): 0.33f > 0.33, e.g. 66/0.33f -> 199 (trunc)
  int neg_cnt = (int)((float)pos_cnt / 0.33f) - pos_cnt;
  if (neg_total < neg_cnt)    neg_cnt = neg_total;
  if (TT - pos_cnt < neg_cnt) neg_cnt = TT - pos_cnt;
  if (neg_cnt < 0)            neg_cnt = 0;

  // Output slices (flat concat in return order: rois, deltas, caps, scores)
  float* rois   = out + (size_t)b * TT * 4;
  float* deltas = out + (size_t)BB * TT * 4 + (size_t)b * TT * 4;
  float* ocaps  = out + (size_t)2 * BB * TT * 4 + (size_t)b * TT * 15;
  float* osc    = out + (size_t)2 * BB * TT * 4 + (size_t)BB * TT * 15 + (size_t)b * TT;

  const int k = tid;
  if (k < TT) {
    if (k < pos_cnt) {
      int i = s_pos[k];
      const float* pp = proposals + ((size_t)b * NP + i) * 4;
      float p0 = pp[0], p1 = pp[1], p2 = pp[2], p3 = pp[3];
      int g = argj[(size_t)b * NP + i];
      const float* gg = gt + ((size_t)b * NG + g) * 4;
      float g0 = gg[0], g1 = gg[1], g2 = gg[2], g3 = gg[3];

      rois[k * 4 + 0] = p0; rois[k * 4 + 1] = p1;
      rois[k * 4 + 2] = p2; rois[k * 4 + 3] = p3;

      float h  = p2 - p0, ww = p3 - p1;
      float cy = p0 + 0.5f * h, cx = p1 + 0.5f * ww;
      float gh = g2 - g0, gw = g3 - g1;
      float gcy = g0 + 0.5f * gh, gcx = g1 + 0.5f * gw;
      deltas[k * 4 + 0] = ((gcy - cy) / h) / 0.1f;
      deltas[k * 4 + 1] = ((gcx - cx) / ww) / 0.1f;
      deltas[k * 4 + 2] = logf(gh / h) / 0.2f;
      deltas[k * 4 + 3] = logf(gw / ww) / 0.2f;

      const int* cp = caps + ((size_t)b * NG + g) * 15;
      for (int c = 0; c < 15; ++c) ocaps[k * 15 + c] = (float)cp[c];
      osc[k] = scores[(size_t)b * NG + g];
    } else {
      if (k < pos_cnt + neg_cnt) {
        int i = s_neg[k - pos_cnt];
        const float* pp = proposals + ((size_t)b * NP + i) * 4;
        rois[k * 4 + 0] = pp[0]; rois[k * 4 + 1] = pp[1];
        rois[k * 4 + 2] = pp[2]; rois[k * 4 + 3] = pp[3];
      } else {
        rois[k * 4 + 0] = 0.0f; rois[k * 4 + 1] = 0.0f;
        rois[k * 4 + 2] = 0.0f; rois[k * 4 + 3] = 0.0f;
      }
      deltas[k * 4 + 0] = 0.0f; deltas[k * 4 + 1] = 0.0f;
      deltas[k * 4 + 2] = 0.0f; deltas[k * 4 + 3] = 0.0f;
      for (int c = 0; c < 15; ++c) ocaps[k * 15 + c] = 0.0f;
      osc[k] = 0.0f;
    }
  }
}

extern "C" void kernel_launch(void* const* d_in, const int* in_sizes, int n_in,
                              void* d_out, int out_size, void* d_ws, size_t ws_size,
                              hipStream_t stream) {
  const float* proposals = (const float*)d_in[0];  // (8,4096,4) f32
  const float* gt        = (const float*)d_in[1];  // (8,512,4)  f32
  const int*   caps      = (const int*)d_in[2];    // (8,512,15) i32
  const float* scores    = (const float*)d_in[3];  // (8,512)    f32
  float* out = (float*)d_out;                      // 38400 f32 (flat tuple)

  char* ws = (char*)d_ws;
  int*          argj = (int*)ws;                                   // 8*4096 i32
  unsigned int* pm   = (unsigned int*)(ws + (size_t)BB * NP * 4);  // 8*128 u32
  unsigned int* nm   = pm + (size_t)BB * NBLK;                     // 8*128 u32

  hipLaunchKernelGGL(iou_phase, dim3(BB * NBLK), dim3(256), 0, stream,
                     proposals, gt, argj, pm, nm);
  hipLaunchKernelGGL(select_phase, dim3(BB), dim3(256), 0, stream,
                     proposals, gt, caps, scores, argj, pm, nm, out);
}

// Round 4
// 80.240 us; speedup vs baseline: 1.6868x; 1.0155x over previous
//
#include <hip/hip_runtime.h>
#include <math.h>

// Problem constants (fixed by reference setup_inputs / module constants)
#define BB   8      // batch
#define NP   4096   // proposals per image
#define NG   512    // gt boxes per image
#define TT   200    // TRAIN_ROIS
#define PMAX 66     // int(200 * 0.33)

#define CH   8      // gt chunks per block
#define PB   32     // proposals per block (256 threads / CH)
#define NBLK (NP / PB)   // 128 proposal-blocks per image

// ---------------------------------------------------------------------------
// Phase A: per proposal, max IoU over gt boxes and first-argmax (jnp.argmax
// tie-break). All 4 waves compact VALID gts into LDS in parallel (stable ->
// ascending original j); invalid columns can never win (iou >= 0 > -1).
// Main loop: 256 threads = 32 proposals x 8 ordered chunks over compacted
// gts; argmax tracked in COMPACTED index (ascending j -> first-max preserved),
// mapped back via one sidx read at the end. Per-iter LDS = one ds_read_b128
// (a2 recomputed in registers, same expr/order as reference -> bit-identical).
// Emits per-block 32-bit pos/neg ballot masks + argj.
// Grid: BB * 128 = 1024 blocks.
// ---------------------------------------------------------------------------
__global__ __launch_bounds__(256) void iou_phase(
    const float* __restrict__ proposals, const float* __restrict__ gt,
    int* __restrict__ argj, unsigned int* __restrict__ posmask,
    unsigned int* __restrict__ negmask) {
#pragma clang fp contract(off)
  const int b     = blockIdx.x >> 7;          // / 128
  const int blk   = blockIdx.x & 127;
  const int pbase = blk * PB;

  __shared__ float4 sgt[NG];    // compacted valid gt boxes (ascending j)
  __shared__ short  sidx[NG];   // their original j
  __shared__ int    s_wcnt[4];
  __shared__ float  rbest[CH][PB];
  __shared__ int    ridx[CH][PB];

  const int tid  = threadIdx.x;
  const int wave = tid >> 6;
  const int lane = tid & 63;

  const int plocal  = tid & (PB - 1);
  const int chunkid = tid >> 5;              // tid / 32
  const int i       = pbase + plocal;

  // Issue the proposal load early so it overlaps gt staging.
  const float4 p = ((const float4*)proposals)[(size_t)b * NP + i];

  // 4-wave parallel stable compaction: wave w covers gts [128w, 128w+128).
  const float4* gtb4 = (const float4*)(gt + (size_t)b * NG * 4);
  const int ja = wave * 128 + lane;
  const int jb = ja + 64;
  const float4 ga = gtb4[ja];
  const float4 gb = gtb4[jb];
  const bool va = (fabsf(ga.x) + fabsf(ga.y) + fabsf(ga.z) + fabsf(ga.w)) > 0.0f;
  const bool vb = (fabsf(gb.x) + fabsf(gb.y) + fabsf(gb.z) + fabsf(gb.w)) > 0.0f;
  const unsigned long long ma = __ballot(va);
  const unsigned long long mb = __ballot(vb);
  if (lane == 0) s_wcnt[wave] = __popcll(ma) + __popcll(mb);
  __syncthreads();

  int wbase = 0;
  for (int w = 0; w < 4; ++w) if (w < wave) wbase += s_wcnt[w];
  const int nv = s_wcnt[0] + s_wcnt[1] + s_wcnt[2] + s_wcnt[3];

  const unsigned long long lower = (1ull << lane) - 1ull;
  if (va) {
    int k = wbase + __popcll(ma & lower);
    sgt[k] = ga; sidx[k] = (short)ja;
  }
  if (vb) {
    int k = wbase + __popcll(ma) + __popcll(mb & lower);
    sgt[k] = gb; sidx[k] = (short)jb;
  }
  __syncthreads();

  const float a1  = (p.z - p.x) * (p.w - p.y);
  const int   csz = (nv + CH - 1) / CH;
  int j0 = chunkid * csz;
  int j1 = j0 + csz; if (j1 > nv) j1 = nv;
  if (j0 > nv) j0 = nv;

  float best = -INFINITY;
  int bk = 0;                                 // compacted winner index
  for (int j = j0; j < j1; ++j) {
    float4 g = sgt[j];                        // 32-lane broadcast (conflict-free)
    // exact reference op order (fp contract off => IEEE, matches numpy/JAX f32)
    float y1 = fmaxf(p.x, g.x);
    float x1 = fmaxf(p.y, g.y);
    float y2 = fminf(p.z, g.z);
    float x2 = fminf(p.w, g.w);
    float inter = fmaxf(x2 - x1, 0.0f) * fmaxf(y2 - y1, 0.0f);
    float a2 = (g.z - g.x) * (g.w - g.y);     // reference a2 expr/order
    float un = a1 + a2 - inter;               // (a1 + a2) - inter
    float iou = inter / (un > 0.0f ? un : 1.0f);
    if (iou > best) { best = iou; bk = j; }   // strict > = first-max (asc j)
  }
  rbest[chunkid][plocal] = best;
  ridx[chunkid][plocal]  = bk;
  __syncthreads();

  // Lanes 0..31 of wave 0 combine the 8 chunk partials in chunk order
  // (chunks cover ascending compacted j -> first-max preserved).
  if (tid < PB) {
    float bb = rbest[0][tid];
    int   bi = ridx[0][tid];
    for (int c = 1; c < CH; ++c) {
      float v = rbest[c][tid];
      if (v > bb) { bb = v; bi = ridx[c][tid]; }
    }
    int borig = (int)sidx[bi];                // compacted -> original j (1 read)
    bool vp  = (fabsf(p.x) + fabsf(p.y) + fabsf(p.z) + fabsf(p.w)) > 0.0f;
    bool isp = vp && (bb >= 0.5f);
    bool isn = vp && (bb <  0.5f);
    unsigned long long mp = __ballot(isp);    // lanes 32..63 inactive -> 0 bits
    unsigned long long mn = __ballot(isn);
    argj[(size_t)b * NP + i] = borig;
    if (tid == 0) {
      posmask[(size_t)b * NBLK + blk] = (unsigned int)mp;
      negmask[(size_t)b * NBLK + blk] = (unsigned int)mn;
    }
  }
}

// ---------------------------------------------------------------------------
// Phase B: per image (1 block). Wave 0 scans the 128 pos masks, wave 1 the
// 128 neg masks, with wave-synchronous shfl_up prefix sums (no barriers),
// bit-emitting ordered index lists (caps PMAX/TT lossless). One barrier,
// then each thread owns one output slot exclusively and writes every output
// element exactly once (d_out is re-poisoned each launch).
// ---------------------------------------------------------------------------
__global__ __launch_bounds__(256) void select_phase(
    const float* __restrict__ proposals, const float* __restrict__ gt,
    const int* __restrict__ caps, const float* __restrict__ scores,
    const int* __restrict__ argj, const unsigned int* __restrict__ posmask,
    const unsigned int* __restrict__ negmask, float* __restrict__ out) {
#pragma clang fp contract(off)
  const int b = blockIdx.x;

  __shared__ int s_pos[PMAX];
  __shared__ int s_neg[TT];
  __shared__ int s_tot[2];

  const int tid  = threadIdx.x;
  const int wave = tid >> 6;
  const int lane = tid & 63;

  if (wave < 2) {
    const unsigned int* msk = (wave == 0 ? posmask : negmask) + (size_t)b * NBLK;
    const int cap = (wave == 0) ? PMAX : TT;
    int* list = (wave == 0) ? s_pos : s_neg;
    // lane l covers masks 2l, 2l+1 == proposals [64l, 64l+64)
    unsigned int m0 = msk[2 * lane];
    unsigned int m1 = msk[2 * lane + 1];
    int cnt = __popc(m0) + __popc(m1);
    int incl = cnt;
    for (int d = 1; d < 64; d <<= 1) {
      int u = __shfl_up(incl, d, 64);
      if (lane >= d) incl += u;
    }
    int base = incl - cnt;
    if (lane == 63) s_tot[wave] = incl;
    while (m0 && base < cap) {
      int bit = __ffs(m0) - 1;
      list[base] = lane * 64 + bit;
      m0 &= m0 - 1; ++base;
    }
    int base1 = base + ((base < cap) ? 0 : 0); // base already advanced past m0
    while (m1 && base1 < cap) {
      int bit = __ffs(m1) - 1;
      list[base1] = lane * 64 + 32 + bit;
      m1 &= m1 - 1; ++base1;
    }
  }
  __syncthreads();

  const int pos_total = s_tot[0];
  const int neg_total = s_tot[1];
  int pos_cnt = pos_total < PMAX ? pos_total : PMAX;
  // f32 semantics (JAX x64-off): 0.33f > 0.33, e.g. 66/0.33f -> 199 (trunc)
  int neg_cnt = (int)((float)pos_cnt / 0.33f) - pos_cnt;
  if (neg_total < neg_cnt)    neg_cnt = neg_total;
  if (TT - pos_cnt < neg_cnt) neg_cnt = TT - pos_cnt;
  if (neg_cnt < 0)            neg_cnt = 0;

  // Output slices (flat concat in return order: rois, deltas, caps, scores)
  float* rois   = out + (size_t)b * TT * 4;
  float* deltas = out + (size_t)BB * TT * 4 + (size_t)b * TT * 4;
  float* ocaps  = out + (size_t)2 * BB * TT * 4 + (size_t)b * TT * 15;
  float* osc    = out + (size_t)2 * BB * TT * 4 + (size_t)BB * TT * 15 + (size_t)b * TT;

  const int k = tid;
  if (k < TT) {
    if (k < pos_cnt) {
      int i = s_pos[k];
      const float* pp = proposals + ((size_t)b * NP + i) * 4;
      float p0 = pp[0], p1 = pp[1], p2 = pp[2], p3 = pp[3];
      int g = argj[(size_t)b * NP + i];
      const float* gg = gt + ((size_t)b * NG + g) * 4;
      float g0 = gg[0], g1 = gg[1], g2 = gg[2], g3 = gg[3];

      rois[k * 4 + 0] = p0; rois[k * 4 + 1] = p1;
      rois[k * 4 + 2] = p2; rois[k * 4 + 3] = p3;

      float h  = p2 - p0, ww = p3 - p1;
      float cy = p0 + 0.5f * h, cx = p1 + 0.5f * ww;
      float gh = g2 - g0, gw = g3 - g1;
      float gcy = g0 + 0.5f * gh, gcx = g1 + 0.5f * gw;
      deltas[k * 4 + 0] = ((gcy - cy) / h) / 0.1f;
      deltas[k * 4 + 1] = ((gcx - cx) / ww) / 0.1f;
      deltas[k * 4 + 2] = logf(gh / h) / 0.2f;
      deltas[k * 4 + 3] = logf(gw / ww) / 0.2f;

      const int* cp = caps + ((size_t)b * NG + g) * 15;
      for (int c = 0; c < 15; ++c) ocaps[k * 15 + c] = (float)cp[c];
      osc[k] = scores[(size_t)b * NG + g];
    } else {
      if (k < pos_cnt + neg_cnt) {
        int i = s_neg[k - pos_cnt];
        const float* pp = proposals + ((size_t)b * NP + i) * 4;
        rois[k * 4 + 0] = pp[0]; rois[k * 4 + 1] = pp[1];
        rois[k * 4 + 2] = pp[2]; rois[k * 4 + 3] = pp[3];
      } else {
        rois[k * 4 + 0] = 0.0f; rois[k * 4 + 1] = 0.0f;
        rois[k * 4 + 2] = 0.0f; rois[k * 4 + 3] = 0.0f;
      }
      deltas[k * 4 + 0] = 0.0f; deltas[k * 4 + 1] = 0.0f;
      deltas[k * 4 + 2] = 0.0f; deltas[k * 4 + 3] = 0.0f;
      for (int c = 0; c < 15; ++c) ocaps[k * 15 + c] = 0.0f;
      osc[k] = 0.0f;
    }
  }
}

extern "C" void kernel_launch(void* const* d_in, const int* in_sizes, int n_in,
                              void* d_out, int out_size, void* d_ws, size_t ws_size,
                              hipStream_t stream) {
  const float* proposals = (const float*)d_in[0];  // (8,4096,4) f32
  const float* gt        = (const float*)d_in[1];  // (8,512,4)  f32
  const int*   caps      = (const int*)d_in[2];    // (8,512,15) i32
  const float* scores    = (const float*)d_in[3];  // (8,512)    f32
  float* out = (float*)d_out;                      // 38400 f32 (flat tuple)

  char* ws = (char*)d_ws;
  int*          argj = (int*)ws;                                   // 8*4096 i32
  unsigned int* pm   = (unsigned int*)(ws + (size_t)BB * NP * 4);  // 8*128 u32
  unsigned int* nm   = pm + (size_t)BB * NBLK;                     // 8*128 u32

  hipLaunchKernelGGL(iou_phase, dim3(BB * NBLK), dim3(256), 0, stream,
                     proposals, gt, argj, pm, nm);
  hipLaunchKernelGGL(select_phase, dim3(BB), dim3(256), 0, stream,
                     proposals, gt, caps, scores, argj, pm, nm, out);
}